// Round 6
// baseline (3156.257 us; speedup 1.0000x reference)
//
#include <hip/hip_runtime.h>
#include <stdint.h>

// R4: split-fp32-into-2xbf16 GEMMs. Proj+scores move to an 8-phase 256^2
// deep-pipelined schedule (T2 swizzle + T3 8-phase + T4 counted vmcnt + T5
// setprio), expressed as a PLAIN bf16 GEMM via K-concatenation:
//   C = Ah@Bh^T + Ah@Bl^T + Al@Bh^T  ==  [Ah|Ah|Al] @ [Bh|Bl|Bh]^T  (K_eff=3K)
// PV keeps the verified fused 128^2 kernel from R1.
// (Resubmitted unchanged in R5 — R4 bench failed on GPU acquisition.)

typedef __attribute__((ext_vector_type(8))) short short8;
typedef __attribute__((ext_vector_type(4))) float f32x4;
typedef __attribute__((ext_vector_type(4))) unsigned short us4;

#define BM 128
#define BN 128
#define BK 32

static __device__ __forceinline__ unsigned short f2bf(float f) {
  unsigned x = __builtin_bit_cast(unsigned, f);
  x += 0x7fffu + ((x >> 16) & 1u);
  return (unsigned short)(x >> 16);
}
static __device__ __forceinline__ float bf2f(unsigned short u) {
  return __builtin_bit_cast(float, (unsigned)u << 16);
}
static __device__ __forceinline__ void gload_lds16(void* lds, const void* g) {
  __builtin_amdgcn_global_load_lds(
      (const __attribute__((address_space(1))) unsigned int*)g,
      (__attribute__((address_space(3))) unsigned int*)lds, 16, 0, 0);
}

// ---------------- elementwise hi/lo split ----------------
__global__ void __launch_bounds__(256)
split_hl(const float* __restrict__ x, unsigned short* __restrict__ h,
         unsigned short* __restrict__ l, int n4) {
  int i = blockIdx.x * 256 + threadIdx.x;
  if (i >= n4) return;
  float4 v = ((const float4*)x)[i];
  float vv[4] = {v.x, v.y, v.z, v.w};
  us4 hh, ll;
#pragma unroll
  for (int j = 0; j < 4; ++j) {
    unsigned short hi = f2bf(vv[j]);
    hh[j] = hi;
    ll[j] = f2bf(vv[j] - bf2f(hi));
  }
  *(us4*)(h + (size_t)i * 4) = hh;
  *(us4*)(l + (size_t)i * 4) = ll;
}

// ---------------- W: transpose + split ----------------
__global__ void __launch_bounds__(256)
wsplit_t(const float* __restrict__ W, unsigned short* __restrict__ th,
         unsigned short* __restrict__ tl, int K, int N) {
  __shared__ float tile[64][65];
  int k0 = blockIdx.y * 64, n0 = blockIdx.x * 64;
  int t = threadIdx.x;
#pragma unroll
  for (int i = 0; i < 16; ++i) {
    int idx = t + i * 256;
    int r = idx >> 6, c = idx & 63;
    tile[r][c] = W[(size_t)(k0 + r) * N + n0 + c];
  }
  __syncthreads();
#pragma unroll
  for (int i = 0; i < 16; ++i) {
    int idx = t + i * 256;
    int nn = idx >> 6, kk = idx & 63;
    float v = tile[kk][nn];
    unsigned short hi = f2bf(v);
    size_t o = (size_t)(n0 + nn) * K + k0 + kk;
    th[o] = hi;
    tl[o] = f2bf(v - bf2f(hi));
  }
}

// ================= 8-phase 256^2 deep-pipelined GEMM =================
// C = scale*(A''@B''^T) + bias, A''=[Ah|Ah|Al], B''=[Bh|Bl|Bh] (K_eff=3K).
// 8 waves (2Mx4N), per-wave 128x64 out. LDS 128KB: 2 dbuf x (A 32KB + B 32KB).
// Swizzle: 16B slot s of row R holds data-group s^(R&7) (pre-swizzled global
// source, linear gload_lds dest, swizzled read). Stage schedule per iteration
// (tiles T=2i in buf0, T+1 in buf1):
//   ph1:A0(T+1)->b1  ph2:A1(T+1)->b1  ph3:B0(T+2)->b0  ph4:B1(T+2)->b0 +vmcnt(4)
//   ph5:A0(T+2)->b0  ph6:A1(T+2)->b0  ph7:B0(T+3)->b1  ph8:B1(T+3)->b1 +vmcnt(4)
// Each staged region's prior readers are barrier-complete; every read happens
// >=3 phases after its stage and after a vmcnt covering it.

struct ZS {
  const unsigned short *Ah, *Al, *Bh, *Bl;
  const float* bias;
  float* outF;
  unsigned short *outH, *outL;
  int mode;  // 0: fp32 out, 1: split out, 2: transposed split out
};
struct GArgs {
  ZS z[4];
  int N, Kreal, nkt, kshift;
  float scale;
  int Srows;
};

#define STAGE8(MAT, H, KT, BUFI) do {                                          \
    int ktc_ = (KT) < nkt ? (KT) : nkt - 1;                                    \
    const unsigned short* base_ = (MAT) ? Bs[ktc_ >> ksh] : As[ktc_ >> ksh];   \
    int rowBase_ = (MAT) ? n0 : m0;                                            \
    int inner_ = (ktc_ & kmask) << 6;                                          \
    _Pragma("unroll")                                                          \
    for (int j_ = 0; j_ < 2; ++j_) {                                           \
      int r_ = j_ * 64 + (tid >> 3);                                           \
      int g_ = (tid & 7) ^ (r_ & 7);                                           \
      gload_lds16(smem + (BUFI) * 65536 + (MAT) * 32768 + (H) * 16384 +        \
                      j_ * 8192 + (tid >> 6) * 1024,                           \
                  base_ + (size_t)(rowBase_ + (H) * 128 + r_) * Kreal +        \
                      inner_ + g_ * 8);                                        \
    }                                                                          \
  } while (0)

#define LDSA8(BUFI, R, ks)                                                     \
  (*(const short8*)(smem + (BUFI) * 65536 + (size_t)(R) * 128 +                \
                    ((((ks) << 2) | lk) ^ ((R) & 7)) * 16))
#define LDSB8(BUFI, R, ks)                                                     \
  (*(const short8*)(smem + (BUFI) * 65536 + 32768 + (size_t)(R) * 128 +        \
                    ((((ks) << 2) | lk) ^ ((R) & 7)) * 16))

#define PHASE8(BUFI, Q, LOADB, STAGE_STMT, DOVM) do {                          \
    short8 af0k0, af0k1, af1k0, af1k1;                                         \
    {                                                                          \
      int R0_ = wr + (2 * (Q)) * 16 + lrow;                                    \
      int R1_ = R0_ + 16;                                                      \
      af0k0 = LDSA8(BUFI, R0_, 0);                                             \
      af0k1 = LDSA8(BUFI, R0_, 1);                                             \
      af1k0 = LDSA8(BUFI, R1_, 0);                                             \
      af1k1 = LDSA8(BUFI, R1_, 1);                                             \
    }                                                                          \
    if (LOADB) {                                                               \
      _Pragma("unroll")                                                        \
      for (int nf_ = 0; nf_ < 4; ++nf_) {                                      \
        int Rn_ = wc + nf_ * 16 + lrow;                                        \
        bfr[nf_][0] = LDSB8(BUFI, Rn_, 0);                                     \
        bfr[nf_][1] = LDSB8(BUFI, Rn_, 1);                                     \
      }                                                                        \
    }                                                                          \
    STAGE_STMT;                                                                \
    __builtin_amdgcn_sched_barrier(0);                                         \
    if (DOVM) asm volatile("s_waitcnt vmcnt(4)" ::: "memory");                 \
    __builtin_amdgcn_s_barrier();                                              \
    asm volatile("s_waitcnt lgkmcnt(0)" ::: "memory");                         \
    __builtin_amdgcn_sched_barrier(0);                                         \
    __builtin_amdgcn_s_setprio(1);                                             \
    _Pragma("unroll")                                                          \
    for (int nf_ = 0; nf_ < 4; ++nf_) {                                        \
      acc[2 * (Q)][nf_] = __builtin_amdgcn_mfma_f32_16x16x32_bf16(             \
          af0k0, bfr[nf_][0], acc[2 * (Q)][nf_], 0, 0, 0);                     \
      acc[2 * (Q)][nf_] = __builtin_amdgcn_mfma_f32_16x16x32_bf16(             \
          af0k1, bfr[nf_][1], acc[2 * (Q)][nf_], 0, 0, 0);                     \
      acc[2 * (Q) + 1][nf_] = __builtin_amdgcn_mfma_f32_16x16x32_bf16(         \
          af1k0, bfr[nf_][0], acc[2 * (Q) + 1][nf_], 0, 0, 0);                 \
      acc[2 * (Q) + 1][nf_] = __builtin_amdgcn_mfma_f32_16x16x32_bf16(         \
          af1k1, bfr[nf_][1], acc[2 * (Q) + 1][nf_], 0, 0, 0);                 \
    }                                                                          \
    __builtin_amdgcn_s_setprio(0);                                             \
    __builtin_amdgcn_s_barrier();                                              \
    __builtin_amdgcn_sched_barrier(0);                                         \
  } while (0)

__global__ void __launch_bounds__(512, 2) gemm8p(GArgs ga) {
  __shared__ __align__(16) char smem[131072];
  const int tid = threadIdx.x;
  const int lane = tid & 63;
  const int lrow = lane & 15, lk = lane >> 4;
  const int wid = tid >> 6;
  const int wr = (wid >> 2) * 128;   // wave row base (2 row-groups)
  const int wc = (wid & 3) * 64;     // wave col base (4 col-groups)
  const int zb = blockIdx.z;
  const ZS zs = ga.z[zb];
  const int m0 = blockIdx.y * 256, n0 = blockIdx.x * 256;
  const int Kreal = ga.Kreal, nkt = ga.nkt, ksh = ga.kshift;
  const int kmask = (1 << ksh) - 1;
  const int N = ga.N;
  const unsigned short* As[3] = {zs.Ah, zs.Ah, zs.Al};
  const unsigned short* Bs[3] = {zs.Bh, zs.Bl, zs.Bh};

  f32x4 acc[8][4] = {};
  short8 bfr[4][2];

  // prologue: A(0),B(0) -> buf0; B(1) -> buf1; wait first 8 of 12 loads.
  STAGE8(0, 0, 0, 0);
  STAGE8(0, 1, 0, 0);
  STAGE8(1, 0, 0, 0);
  STAGE8(1, 1, 0, 0);
  STAGE8(1, 0, 1, 1);
  STAGE8(1, 1, 1, 1);
  __builtin_amdgcn_sched_barrier(0);
  asm volatile("s_waitcnt vmcnt(4)" ::: "memory");
  __builtin_amdgcn_s_barrier();
  __builtin_amdgcn_sched_barrier(0);

  const int niter = nkt >> 1;
  for (int i = 0; i < niter; ++i) {
    int T = 2 * i;
    PHASE8(0, 0, true,  STAGE8(0, 0, T + 1, 1), false);
    PHASE8(0, 1, false, STAGE8(0, 1, T + 1, 1), false);
    PHASE8(0, 2, false, STAGE8(1, 0, T + 2, 0), false);
    PHASE8(0, 3, false, STAGE8(1, 1, T + 2, 0), true);
    PHASE8(1, 0, true,  STAGE8(0, 0, T + 2, 0), false);
    PHASE8(1, 1, false, STAGE8(0, 1, T + 2, 0), false);
    PHASE8(1, 2, false, STAGE8(1, 0, T + 3, 1), false);
    PHASE8(1, 3, false, STAGE8(1, 1, T + 3, 1), true);
  }

  // epilogue: C/D layout col=lane&15, row=(lane>>4)*4+r
#pragma unroll
  for (int mf = 0; mf < 8; ++mf) {
#pragma unroll
    for (int nf = 0; nf < 4; ++nf) {
      int gcol = n0 + wc + nf * 16 + lrow;
      float bv = zs.bias ? zs.bias[gcol] : 0.0f;
#pragma unroll
      for (int r = 0; r < 4; ++r) {
        int grow = m0 + wr + mf * 16 + lk * 4 + r;
        float v = acc[mf][nf][r] * ga.scale + bv;
        if (zs.mode == 0) {
          zs.outF[(size_t)grow * N + gcol] = v;
        } else if (zs.mode == 1) {
          unsigned short hi = f2bf(v);
          size_t o = (size_t)grow * N + gcol;
          zs.outH[o] = hi;
          zs.outL[o] = f2bf(v - bf2f(hi));
        } else {
          int bb = grow / ga.Srows, s = grow - bb * ga.Srows;
          size_t o = ((size_t)bb * N + gcol) * ga.Srows + s;
          unsigned short hi = f2bf(v);
          zs.outH[o] = hi;
          zs.outL[o] = f2bf(v - bf2f(hi));
        }
      }
    }
  }
}

// ---------------- fused split-bf16 GEMM (128^2, R1-verified) — PV only -------
template <int MODE>
__global__ void __launch_bounds__(256)
gemm_split(const unsigned short* __restrict__ Ah, const unsigned short* __restrict__ Al,
           const unsigned short* __restrict__ Bh, const unsigned short* __restrict__ Bl,
           long sAb, long sBb, int M, int N, int K,
           const float* __restrict__ bias, float scale,
           float* __restrict__ outF, long sOb,
           unsigned short* __restrict__ outH, unsigned short* __restrict__ outL,
           int Srows) {
  __shared__ __align__(16) unsigned short Lds[4 * BM * BK];
  const int t = threadIdx.x;
  const int wave = t >> 6, lane = t & 63;
  const int wr = (wave >> 1) * 64, wc = (wave & 1) * 64;
  const long zb = blockIdx.z;
  const int m0 = blockIdx.y * BM, n0 = blockIdx.x * BN;
  Ah += zb * sAb; Al += zb * sAb;
  Bh += zb * sBb; Bl += zb * sBb;

  f32x4 acc[4][4] = {};
  const int lrow = lane & 15, lk = lane >> 4;
  char* AhT = (char*)Lds;
  char* AlT = AhT + 8192;
  char* BhT = AlT + 8192;
  char* BlT = BhT + 8192;
  const int sw = (lrow >> 1) & 3;
  const int slotB16 = (lk ^ sw) * 16;

  for (int kt = 0; kt < K; kt += BK) {
#pragma unroll
    for (int i = 0; i < 2; ++i) {
      int c = i * 256 + t;
      int row = c >> 2;
      int cs = (c & 3) ^ ((c >> 3) & 3);
      size_t ldsOff = (size_t)(i * 256 + wave * 64) * 16;
      size_t gA = (size_t)(m0 + row) * K + kt + cs * 8;
      size_t gB = (size_t)(n0 + row) * K + kt + cs * 8;
      gload_lds16(AhT + ldsOff, Ah + gA);
      gload_lds16(AlT + ldsOff, Al + gA);
      gload_lds16(BhT + ldsOff, Bh + gB);
      gload_lds16(BlT + ldsOff, Bl + gB);
    }
    __syncthreads();

    const char* Ap[3] = {AhT, AhT, AlT};
    const char* Bp[3] = {BhT, BlT, BhT};
#pragma unroll
    for (int p = 0; p < 3; ++p) {
      short8 af[4], bfv[4];
#pragma unroll
      for (int m = 0; m < 4; ++m)
        af[m] = *(const short8*)(Ap[p] + (size_t)((wr + m * 16 + lrow) * 64) + slotB16);
#pragma unroll
      for (int n = 0; n < 4; ++n)
        bfv[n] = *(const short8*)(Bp[p] + (size_t)((wc + n * 16 + lrow) * 64) + slotB16);
#pragma unroll
      for (int m = 0; m < 4; ++m)
#pragma unroll
        for (int n = 0; n < 4; ++n)
          acc[m][n] = __builtin_amdgcn_mfma_f32_16x16x32_bf16(af[m], bfv[n], acc[m][n], 0, 0, 0);
    }
    __syncthreads();
  }

#pragma unroll
  for (int m = 0; m < 4; ++m) {
#pragma unroll
    for (int n = 0; n < 4; ++n) {
      int gcol = n0 + wc + n * 16 + lrow;
      float bv = bias ? bias[gcol] : 0.0f;
#pragma unroll
      for (int r = 0; r < 4; ++r) {
        int grow = m0 + wr + m * 16 + lk * 4 + r;
        float v = acc[m][n][r] * scale + bv;
        if (MODE == 0) {
          outF[zb * sOb + (size_t)grow * N + gcol] = v;
        } else if (MODE == 1) {
          unsigned short hi = f2bf(v);
          size_t o = (size_t)grow * N + gcol;
          outH[o] = hi;
          outL[o] = f2bf(v - bf2f(hi));
        } else {
          int bb = grow / Srows, s = grow - bb * Srows;
          size_t o = (size_t)bb * N * Srows + (size_t)gcol * Srows + s;
          unsigned short hi = f2bf(v);
          outH[o] = hi;
          outL[o] = f2bf(v - bf2f(hi));
        }
      }
    }
  }
}

// ---------------- row softmax ----------------
__global__ void __launch_bounds__(256)
softmax_rows(const float* __restrict__ sc, unsigned short* __restrict__ ph,
             unsigned short* __restrict__ pl, int S) {
  const size_t row = blockIdx.x;
  const float* sr = sc + row * S;
  int t = threadIdx.x;
  float x[8];
  const float4* s4 = (const float4*)sr;
#pragma unroll
  for (int i = 0; i < 2; ++i) {
    float4 v = s4[t + i * 256];
    x[i * 4 + 0] = v.x; x[i * 4 + 1] = v.y; x[i * 4 + 2] = v.z; x[i * 4 + 3] = v.w;
  }
  float m = x[0];
#pragma unroll
  for (int j = 1; j < 8; ++j) m = fmaxf(m, x[j]);
#pragma unroll
  for (int off = 32; off; off >>= 1) m = fmaxf(m, __shfl_xor(m, off));
  __shared__ float red[4];
  if ((t & 63) == 0) red[t >> 6] = m;
  __syncthreads();
  m = fmaxf(fmaxf(red[0], red[1]), fmaxf(red[2], red[3]));
  float e[8];
  float sum = 0.f;
#pragma unroll
  for (int j = 0; j < 8; ++j) { e[j] = __expf(x[j] - m); sum += e[j]; }
#pragma unroll
  for (int off = 32; off; off >>= 1) sum += __shfl_xor(sum, off);
  __shared__ float red2[4];
  if ((t & 63) == 0) red2[t >> 6] = sum;
  __syncthreads();
  sum = red2[0] + red2[1] + red2[2] + red2[3];
  float rinv = 1.0f / sum;
#pragma unroll
  for (int i = 0; i < 2; ++i) {
    us4 hh, ll;
#pragma unroll
    for (int j = 0; j < 4; ++j) {
      float p = e[i * 4 + j] * rinv;
      unsigned short hi = f2bf(p);
      hh[j] = hi;
      ll[j] = f2bf(p - bf2f(hi));
    }
    size_t o = row * S + (size_t)(t + i * 256) * 4;
    *(us4*)(ph + o) = hh;
    *(us4*)(pl + o) = ll;
  }
}

extern "C" void kernel_launch(void* const* d_in, const int* in_sizes, int n_in,
                              void* d_out, int out_size, void* d_ws, size_t ws_size,
                              hipStream_t stream) {
  const int B = 4, S = 2048, D = 1024, DK = 1024, DV = 1024;
  const float* q = (const float*)d_in[0];
  const float* k = (const float*)d_in[1];
  const float* v = (const float*)d_in[2];
  const float* Wq = (const float*)d_in[3];
  const float* Wk = (const float*)d_in[4];
  const float* Wv = (const float*)d_in[5];
  const float* bq = (const float*)d_in[6];
  const float* bk = (const float*)d_in[7];
  const float* bv = (const float*)d_in[8];

  char* ws = (char*)d_ws;
  const size_t MBy = 1024 * 1024;
  unsigned short* qh = (unsigned short*)(ws + 0 * MBy);
  unsigned short* ql = (unsigned short*)(ws + 16 * MBy);
  unsigned short* kh = (unsigned short*)(ws + 32 * MBy);
  unsigned short* kl = (unsigned short*)(ws + 48 * MBy);
  unsigned short* vh = (unsigned short*)(ws + 64 * MBy);
  unsigned short* vl = (unsigned short*)(ws + 80 * MBy);
  unsigned short* wqth = (unsigned short*)(ws + 96 * MBy);
  unsigned short* wqtl = (unsigned short*)(ws + 98 * MBy);
  unsigned short* wkth = (unsigned short*)(ws + 100 * MBy);
  unsigned short* wktl = (unsigned short*)(ws + 102 * MBy);
  unsigned short* wvth = (unsigned short*)(ws + 104 * MBy);
  unsigned short* wvtl = (unsigned short*)(ws + 106 * MBy);
  unsigned short* Qh = (unsigned short*)(ws + 108 * MBy);
  unsigned short* Ql = (unsigned short*)(ws + 124 * MBy);
  unsigned short* Kh = (unsigned short*)(ws + 140 * MBy);
  unsigned short* Kl = (unsigned short*)(ws + 156 * MBy);
  unsigned short* Vth = (unsigned short*)(ws + 172 * MBy);
  unsigned short* Vtl = (unsigned short*)(ws + 188 * MBy);
  float* scores = (float*)(ws + 0 * MBy);
  unsigned short* Ph = (unsigned short*)(ws + 64 * MBy);
  unsigned short* Pl = (unsigned short*)(ws + 108 * MBy);

  const int n4 = B * S * D / 4;
  split_hl<<<n4 / 256, 256, 0, stream>>>(q, qh, ql, n4);
  split_hl<<<n4 / 256, 256, 0, stream>>>(k, kh, kl, n4);
  split_hl<<<n4 / 256, 256, 0, stream>>>(v, vh, vl, n4);

  wsplit_t<<<dim3(DK / 64, D / 64), 256, 0, stream>>>(Wq, wqth, wqtl, D, DK);
  wsplit_t<<<dim3(DK / 64, D / 64), 256, 0, stream>>>(Wk, wkth, wktl, D, DK);
  wsplit_t<<<dim3(DV / 64, D / 64), 256, 0, stream>>>(Wv, wvth, wvtl, D, DV);

  // projections: one z-batched 8-phase dispatch (z0=Q, z1=K, z2=V^T out)
  {
    GArgs pa{};
    pa.z[0] = {qh, ql, wqth, wqtl, bq, nullptr, Qh, Ql, 1};
    pa.z[1] = {kh, kl, wkth, wktl, bk, nullptr, Kh, Kl, 1};
    pa.z[2] = {vh, vl, wvth, wvtl, bv, nullptr, Vth, Vtl, 2};
    pa.N = DK; pa.Kreal = D; pa.nkt = 48; pa.kshift = 4;
    pa.scale = 1.0f; pa.Srows = S;
    gemm8p<<<dim3(DK / 256, (B * S) / 256, 3), 512, 0, stream>>>(pa);
  }

  // scores: per-batch [S,S] = Q @ K^T * (1/32), 8-phase
  {
    GArgs sa{};
    for (int b = 0; b < 4; ++b) {
      sa.z[b] = {Qh + (size_t)b * S * DK, Ql + (size_t)b * S * DK,
                 Kh + (size_t)b * S * DK, Kl + (size_t)b * S * DK,
                 nullptr, scores + (size_t)b * S * S, nullptr, nullptr, 0};
    }
    sa.N = S; sa.Kreal = DK; sa.nkt = 48; sa.kshift = 4;
    sa.scale = 0.03125f; sa.Srows = S;
    gemm8p<<<dim3(S / 256, S / 256, B), 512, 0, stream>>>(sa);
  }

  softmax_rows<<<B * S, 256, 0, stream>>>(scores, Ph, Pl, S);

  // out = P @ V : A = P [S,S], B = V^T [DV,S]  (fused 128^2 kernel)
  gemm_split<0><<<dim3(DV / BN, S / BM, B), 256, 0, stream>>>(
      Ph, Pl, Vth, Vtl, (long)S * S, (long)DV * S, S, DV, S, nullptr, 1.0f,
      (float*)d_out, (long)S * DV, nullptr, nullptr, S);
}

// Round 8
// 3096.368 us; speedup vs baseline: 1.0193x; 1.0193x over previous
//
#include <hip/hip_runtime.h>
#include <stdint.h>

// R6: fix the R4 8-phase kernel's catastrophic accumulator spill (WRITE_SIZE
// 4.95 GB of scratch traffic, VGPR_Count=88 < 128-reg accumulator):
//  - __launch_bounds__(512) + amdgpu_waves_per_eu(1,2)  (was (512,2) which
//    capped the register budget and spilled acc[8][4] to scratch)
//  - no runtime-indexed pointer arrays (As[]/Bs[] -> ternary selects;
//    ga.z[zb] -> constant-index if-chain)   [rule #20]
// Schedule, swizzle, and all other kernels unchanged from R4/R5.
// (Resubmitted unchanged in R7 — R6 bench failed on GPU acquisition.)

typedef __attribute__((ext_vector_type(8))) short short8;
typedef __attribute__((ext_vector_type(4))) float f32x4;
typedef __attribute__((ext_vector_type(4))) unsigned short us4;

#define BM 128
#define BN 128
#define BK 32

static __device__ __forceinline__ unsigned short f2bf(float f) {
  unsigned x = __builtin_bit_cast(unsigned, f);
  x += 0x7fffu + ((x >> 16) & 1u);
  return (unsigned short)(x >> 16);
}
static __device__ __forceinline__ float bf2f(unsigned short u) {
  return __builtin_bit_cast(float, (unsigned)u << 16);
}
static __device__ __forceinline__ void gload_lds16(void* lds, const void* g) {
  __builtin_amdgcn_global_load_lds(
      (const __attribute__((address_space(1))) unsigned int*)g,
      (__attribute__((address_space(3))) unsigned int*)lds, 16, 0, 0);
}

// ---------------- elementwise hi/lo split ----------------
__global__ void __launch_bounds__(256)
split_hl(const float* __restrict__ x, unsigned short* __restrict__ h,
         unsigned short* __restrict__ l, int n4) {
  int i = blockIdx.x * 256 + threadIdx.x;
  if (i >= n4) return;
  float4 v = ((const float4*)x)[i];
  float vv[4] = {v.x, v.y, v.z, v.w};
  us4 hh, ll;
#pragma unroll
  for (int j = 0; j < 4; ++j) {
    unsigned short hi = f2bf(vv[j]);
    hh[j] = hi;
    ll[j] = f2bf(vv[j] - bf2f(hi));
  }
  *(us4*)(h + (size_t)i * 4) = hh;
  *(us4*)(l + (size_t)i * 4) = ll;
}

// ---------------- W: transpose + split ----------------
__global__ void __launch_bounds__(256)
wsplit_t(const float* __restrict__ W, unsigned short* __restrict__ th,
         unsigned short* __restrict__ tl, int K, int N) {
  __shared__ float tile[64][65];
  int k0 = blockIdx.y * 64, n0 = blockIdx.x * 64;
  int t = threadIdx.x;
#pragma unroll
  for (int i = 0; i < 16; ++i) {
    int idx = t + i * 256;
    int r = idx >> 6, c = idx & 63;
    tile[r][c] = W[(size_t)(k0 + r) * N + n0 + c];
  }
  __syncthreads();
#pragma unroll
  for (int i = 0; i < 16; ++i) {
    int idx = t + i * 256;
    int nn = idx >> 6, kk = idx & 63;
    float v = tile[kk][nn];
    unsigned short hi = f2bf(v);
    size_t o = (size_t)(n0 + nn) * K + k0 + kk;
    th[o] = hi;
    tl[o] = f2bf(v - bf2f(hi));
  }
}

// ================= 8-phase 256^2 deep-pipelined GEMM =================
// C = scale*(A''@B''^T) + bias, A''=[Ah|Ah|Al], B''=[Bh|Bl|Bh] (K_eff=3K).
// 8 waves (2Mx4N), per-wave 128x64 out. LDS 128KB: 2 dbuf x (A 32KB + B 32KB).
// Swizzle: 16B slot s of row R holds data-group s^(R&7). Stage schedule per
// iteration (tiles T=2i in buf0, T+1 in buf1):
//   ph1:A0(T+1)->b1  ph2:A1(T+1)->b1  ph3:B0(T+2)->b0  ph4:B1(T+2)->b0 +vmcnt(4)
//   ph5:A0(T+2)->b0  ph6:A1(T+2)->b0  ph7:B0(T+3)->b1  ph8:B1(T+3)->b1 +vmcnt(4)

struct ZS {
  const unsigned short *Ah, *Al, *Bh, *Bl;
  const float* bias;
  float* outF;
  unsigned short *outH, *outL;
  int mode;  // 0: fp32 out, 1: split out, 2: transposed split out
};
struct GArgs {
  ZS z[4];
  int N, Kreal, nkt, kshift;
  float scale;
  int Srows;
};

#define STAGE8(MAT, H, KT, BUFI) do {                                          \
    int ktc_ = (KT) < nkt ? (KT) : nkt - 1;                                    \
    int grp_ = ktc_ >> ksh;                                                    \
    const unsigned short* base_ =                                              \
        (MAT) ? ((grp_ == 1) ? Bl_ : Bh_) : ((grp_ == 2) ? Al_ : Ah_);         \
    int rowBase_ = (MAT) ? n0 : m0;                                            \
    int inner_ = (ktc_ & kmask) << 6;                                          \
    _Pragma("unroll")                                                          \
    for (int j_ = 0; j_ < 2; ++j_) {                                           \
      int r_ = j_ * 64 + (tid >> 3);                                           \
      int g_ = (tid & 7) ^ (r_ & 7);                                           \
      gload_lds16(smem + (BUFI) * 65536 + (MAT) * 32768 + (H) * 16384 +        \
                      j_ * 8192 + (tid >> 6) * 1024,                           \
                  base_ + (size_t)(rowBase_ + (H) * 128 + r_) * Kreal +        \
                      inner_ + g_ * 8);                                        \
    }                                                                          \
  } while (0)

#define LDSA8(BUFI, R, ks)                                                     \
  (*(const short8*)(smem + (BUFI) * 65536 + (size_t)(R) * 128 +                \
                    ((((ks) << 2) | lk) ^ ((R) & 7)) * 16))
#define LDSB8(BUFI, R, ks)                                                     \
  (*(const short8*)(smem + (BUFI) * 65536 + 32768 + (size_t)(R) * 128 +        \
                    ((((ks) << 2) | lk) ^ ((R) & 7)) * 16))

#define PHASE8(BUFI, Q, LOADB, STAGE_STMT, DOVM) do {                          \
    short8 af0k0, af0k1, af1k0, af1k1;                                         \
    {                                                                          \
      int R0_ = wr + (2 * (Q)) * 16 + lrow;                                    \
      int R1_ = R0_ + 16;                                                      \
      af0k0 = LDSA8(BUFI, R0_, 0);                                             \
      af0k1 = LDSA8(BUFI, R0_, 1);                                             \
      af1k0 = LDSA8(BUFI, R1_, 0);                                             \
      af1k1 = LDSA8(BUFI, R1_, 1);                                             \
    }                                                                          \
    if (LOADB) {                                                               \
      _Pragma("unroll")                                                        \
      for (int nf_ = 0; nf_ < 4; ++nf_) {                                      \
        int Rn_ = wc + nf_ * 16 + lrow;                                        \
        bfr[nf_][0] = LDSB8(BUFI, Rn_, 0);                                     \
        bfr[nf_][1] = LDSB8(BUFI, Rn_, 1);                                     \
      }                                                                        \
    }                                                                          \
    STAGE_STMT;                                                                \
    __builtin_amdgcn_sched_barrier(0);                                         \
    if (DOVM) asm volatile("s_waitcnt vmcnt(4)" ::: "memory");                 \
    __builtin_amdgcn_s_barrier();                                              \
    asm volatile("s_waitcnt lgkmcnt(0)" ::: "memory");                         \
    __builtin_amdgcn_sched_barrier(0);                                         \
    __builtin_amdgcn_s_setprio(1);                                             \
    _Pragma("unroll")                                                          \
    for (int nf_ = 0; nf_ < 4; ++nf_) {                                        \
      acc[2 * (Q)][nf_] = __builtin_amdgcn_mfma_f32_16x16x32_bf16(             \
          af0k0, bfr[nf_][0], acc[2 * (Q)][nf_], 0, 0, 0);                     \
      acc[2 * (Q)][nf_] = __builtin_amdgcn_mfma_f32_16x16x32_bf16(             \
          af0k1, bfr[nf_][1], acc[2 * (Q)][nf_], 0, 0, 0);                     \
      acc[2 * (Q) + 1][nf_] = __builtin_amdgcn_mfma_f32_16x16x32_bf16(         \
          af1k0, bfr[nf_][0], acc[2 * (Q) + 1][nf_], 0, 0, 0);                 \
      acc[2 * (Q) + 1][nf_] = __builtin_amdgcn_mfma_f32_16x16x32_bf16(         \
          af1k1, bfr[nf_][1], acc[2 * (Q) + 1][nf_], 0, 0, 0);                 \
    }                                                                          \
    __builtin_amdgcn_s_setprio(0);                                             \
    __builtin_amdgcn_s_barrier();                                              \
    __builtin_amdgcn_sched_barrier(0);                                         \
  } while (0)

__attribute__((amdgpu_waves_per_eu(1, 2))) __global__ void
__launch_bounds__(512) gemm8p(GArgs ga) {
  __shared__ __align__(16) char smem[131072];
  const int tid = threadIdx.x;
  const int lane = tid & 63;
  const int lrow = lane & 15, lk = lane >> 4;
  const int wid = tid >> 6;
  const int wr = (wid >> 2) * 128;   // wave row base (2 row-groups)
  const int wc = (wid & 3) * 64;     // wave col base (4 col-groups)
  const int zb = blockIdx.z;
  // constant-index select (wave-uniform) -- avoids stack-indexed byval array
  ZS zs;
  if (zb == 0) zs = ga.z[0];
  else if (zb == 1) zs = ga.z[1];
  else if (zb == 2) zs = ga.z[2];
  else zs = ga.z[3];
  const int m0 = blockIdx.y * 256, n0 = blockIdx.x * 256;
  const int Kreal = ga.Kreal, nkt = ga.nkt, ksh = ga.kshift;
  const int kmask = (1 << ksh) - 1;
  const int N = ga.N;
  const unsigned short* Ah_ = zs.Ah;
  const unsigned short* Al_ = zs.Al;
  const unsigned short* Bh_ = zs.Bh;
  const unsigned short* Bl_ = zs.Bl;

  f32x4 acc[8][4] = {};
  short8 bfr[4][2];

  // prologue: A(0),B(0) -> buf0; B(1) -> buf1; wait first 8 of 12 loads.
  STAGE8(0, 0, 0, 0);
  STAGE8(0, 1, 0, 0);
  STAGE8(1, 0, 0, 0);
  STAGE8(1, 1, 0, 0);
  STAGE8(1, 0, 1, 1);
  STAGE8(1, 1, 1, 1);
  __builtin_amdgcn_sched_barrier(0);
  asm volatile("s_waitcnt vmcnt(4)" ::: "memory");
  __builtin_amdgcn_s_barrier();
  __builtin_amdgcn_sched_barrier(0);

  const int niter = nkt >> 1;
  for (int i = 0; i < niter; ++i) {
    int T = 2 * i;
    PHASE8(0, 0, true,  STAGE8(0, 0, T + 1, 1), false);
    PHASE8(0, 1, false, STAGE8(0, 1, T + 1, 1), false);
    PHASE8(0, 2, false, STAGE8(1, 0, T + 2, 0), false);
    PHASE8(0, 3, false, STAGE8(1, 1, T + 2, 0), true);
    PHASE8(1, 0, true,  STAGE8(0, 0, T + 2, 0), false);
    PHASE8(1, 1, false, STAGE8(0, 1, T + 2, 0), false);
    PHASE8(1, 2, false, STAGE8(1, 0, T + 3, 1), false);
    PHASE8(1, 3, false, STAGE8(1, 1, T + 3, 1), true);
  }

  // epilogue: C/D layout col=lane&15, row=(lane>>4)*4+r
#pragma unroll
  for (int mf = 0; mf < 8; ++mf) {
#pragma unroll
    for (int nf = 0; nf < 4; ++nf) {
      int gcol = n0 + wc + nf * 16 + lrow;
      float bv = zs.bias ? zs.bias[gcol] : 0.0f;
#pragma unroll
      for (int r = 0; r < 4; ++r) {
        int grow = m0 + wr + mf * 16 + lk * 4 + r;
        float v = acc[mf][nf][r] * ga.scale + bv;
        if (zs.mode == 0) {
          zs.outF[(size_t)grow * N + gcol] = v;
        } else if (zs.mode == 1) {
          unsigned short hi = f2bf(v);
          size_t o = (size_t)grow * N + gcol;
          zs.outH[o] = hi;
          zs.outL[o] = f2bf(v - bf2f(hi));
        } else {
          int bb = grow / ga.Srows, s = grow - bb * ga.Srows;
          size_t o = ((size_t)bb * N + gcol) * ga.Srows + s;
          unsigned short hi = f2bf(v);
          zs.outH[o] = hi;
          zs.outL[o] = f2bf(v - bf2f(hi));
        }
      }
    }
  }
}

// ---------------- fused split-bf16 GEMM (128^2, R1-verified) — PV only -------
template <int MODE>
__global__ void __launch_bounds__(256)
gemm_split(const unsigned short* __restrict__ Ah, const unsigned short* __restrict__ Al,
           const unsigned short* __restrict__ Bh, const unsigned short* __restrict__ Bl,
           long sAb, long sBb, int M, int N, int K,
           const float* __restrict__ bias, float scale,
           float* __restrict__ outF, long sOb,
           unsigned short* __restrict__ outH, unsigned short* __restrict__ outL,
           int Srows) {
  __shared__ __align__(16) unsigned short Lds[4 * BM * BK];
  const int t = threadIdx.x;
  const int wave = t >> 6, lane = t & 63;
  const int wr = (wave >> 1) * 64, wc = (wave & 1) * 64;
  const long zb = blockIdx.z;
  const int m0 = blockIdx.y * BM, n0 = blockIdx.x * BN;
  Ah += zb * sAb; Al += zb * sAb;
  Bh += zb * sBb; Bl += zb * sBb;

  f32x4 acc[4][4] = {};
  const int lrow = lane & 15, lk = lane >> 4;
  char* AhT = (char*)Lds;
  char* AlT = AhT + 8192;
  char* BhT = AlT + 8192;
  char* BlT = BhT + 8192;
  const int sw = (lrow >> 1) & 3;
  const int slotB16 = (lk ^ sw) * 16;

  for (int kt = 0; kt < K; kt += BK) {
#pragma unroll
    for (int i = 0; i < 2; ++i) {
      int c = i * 256 + t;
      int row = c >> 2;
      int cs = (c & 3) ^ ((c >> 3) & 3);
      size_t ldsOff = (size_t)(i * 256 + wave * 64) * 16;
      size_t gA = (size_t)(m0 + row) * K + kt + cs * 8;
      size_t gB = (size_t)(n0 + row) * K + kt + cs * 8;
      gload_lds16(AhT + ldsOff, Ah + gA);
      gload_lds16(AlT + ldsOff, Al + gA);
      gload_lds16(BhT + ldsOff, Bh + gB);
      gload_lds16(BlT + ldsOff, Bl + gB);
    }
    __syncthreads();

    const char* Ap[3] = {AhT, AhT, AlT};
    const char* Bp[3] = {BhT, BlT, BhT};
#pragma unroll
    for (int p = 0; p < 3; ++p) {
      short8 af[4], bfv[4];
#pragma unroll
      for (int m = 0; m < 4; ++m)
        af[m] = *(const short8*)(Ap[p] + (size_t)((wr + m * 16 + lrow) * 64) + slotB16);
#pragma unroll
      for (int n = 0; n < 4; ++n)
        bfv[n] = *(const short8*)(Bp[p] + (size_t)((wc + n * 16 + lrow) * 64) + slotB16);
#pragma unroll
      for (int m = 0; m < 4; ++m)
#pragma unroll
        for (int n = 0; n < 4; ++n)
          acc[m][n] = __builtin_amdgcn_mfma_f32_16x16x32_bf16(af[m], bfv[n], acc[m][n], 0, 0, 0);
    }
    __syncthreads();
  }

#pragma unroll
  for (int m = 0; m < 4; ++m) {
#pragma unroll
    for (int n = 0; n < 4; ++n) {
      int gcol = n0 + wc + n * 16 + lrow;
      float bv = bias ? bias[gcol] : 0.0f;
#pragma unroll
      for (int r = 0; r < 4; ++r) {
        int grow = m0 + wr + m * 16 + lk * 4 + r;
        float v = acc[m][n][r] * scale + bv;
        if (MODE == 0) {
          outF[zb * sOb + (size_t)grow * N + gcol] = v;
        } else if (MODE == 1) {
          unsigned short hi = f2bf(v);
          size_t o = (size_t)grow * N + gcol;
          outH[o] = hi;
          outL[o] = f2bf(v - bf2f(hi));
        } else {
          int bb = grow / Srows, s = grow - bb * Srows;
          size_t o = (size_t)bb * N * Srows + (size_t)gcol * Srows + s;
          unsigned short hi = f2bf(v);
          outH[o] = hi;
          outL[o] = f2bf(v - bf2f(hi));
        }
      }
    }
  }
}

// ---------------- row softmax ----------------
__global__ void __launch_bounds__(256)
softmax_rows(const float* __restrict__ sc, unsigned short* __restrict__ ph,
             unsigned short* __restrict__ pl, int S) {
  const size_t row = blockIdx.x;
  const float* sr = sc + row * S;
  int t = threadIdx.x;
  float x[8];
  const float4* s4 = (const float4*)sr;
#pragma unroll
  for (int i = 0; i < 2; ++i) {
    float4 v = s4[t + i * 256];
    x[i * 4 + 0] = v.x; x[i * 4 + 1] = v.y; x[i * 4 + 2] = v.z; x[i * 4 + 3] = v.w;
  }
  float m = x[0];
#pragma unroll
  for (int j = 1; j < 8; ++j) m = fmaxf(m, x[j]);
#pragma unroll
  for (int off = 32; off; off >>= 1) m = fmaxf(m, __shfl_xor(m, off));
  __shared__ float red[4];
  if ((t & 63) == 0) red[t >> 6] = m;
  __syncthreads();
  m = fmaxf(fmaxf(red[0], red[1]), fmaxf(red[2], red[3]));
  float e[8];
  float sum = 0.f;
#pragma unroll
  for (int j = 0; j < 8; ++j) { e[j] = __expf(x[j] - m); sum += e[j]; }
#pragma unroll
  for (int off = 32; off; off >>= 1) sum += __shfl_xor(sum, off);
  __shared__ float red2[4];
  if ((t & 63) == 0) red2[t >> 6] = sum;
  __syncthreads();
  sum = red2[0] + red2[1] + red2[2] + red2[3];
  float rinv = 1.0f / sum;
#pragma unroll
  for (int i = 0; i < 2; ++i) {
    us4 hh, ll;
#pragma unroll
    for (int j = 0; j < 4; ++j) {
      float p = e[i * 4 + j] * rinv;
      unsigned short hi = f2bf(p);
      hh[j] = hi;
      ll[j] = f2bf(p - bf2f(hi));
    }
    size_t o = row * S + (size_t)(t + i * 256) * 4;
    *(us4*)(ph + o) = hh;
    *(us4*)(pl + o) = ll;
  }
}

extern "C" void kernel_launch(void* const* d_in, const int* in_sizes, int n_in,
                              void* d_out, int out_size, void* d_ws, size_t ws_size,
                              hipStream_t stream) {
  const int B = 4, S = 2048, D = 1024, DK = 1024, DV = 1024;
  const float* q = (const float*)d_in[0];
  const float* k = (const float*)d_in[1];
  const float* v = (const float*)d_in[2];
  const float* Wq = (const float*)d_in[3];
  const float* Wk = (const float*)d_in[4];
  const float* Wv = (const float*)d_in[5];
  const float* bq = (const float*)d_in[6];
  const float* bk = (const float*)d_in[7];
  const float* bv = (const float*)d_in[8];

  char* ws = (char*)d_ws;
  const size_t MBy = 1024 * 1024;
  unsigned short* qh = (unsigned short*)(ws + 0 * MBy);
  unsigned short* ql = (unsigned short*)(ws + 16 * MBy);
  unsigned short* kh = (unsigned short*)(ws + 32 * MBy);
  unsigned short* kl = (unsigned short*)(ws + 48 * MBy);
  unsigned short* vh = (unsigned short*)(ws + 64 * MBy);
  unsigned short* vl = (unsigned short*)(ws + 80 * MBy);
  unsigned short* wqth = (unsigned short*)(ws + 96 * MBy);
  unsigned short* wqtl = (unsigned short*)(ws + 98 * MBy);
  unsigned short* wkth = (unsigned short*)(ws + 100 * MBy);
  unsigned short* wktl = (unsigned short*)(ws + 102 * MBy);
  unsigned short* wvth = (unsigned short*)(ws + 104 * MBy);
  unsigned short* wvtl = (unsigned short*)(ws + 106 * MBy);
  unsigned short* Qh = (unsigned short*)(ws + 108 * MBy);
  unsigned short* Ql = (unsigned short*)(ws + 124 * MBy);
  unsigned short* Kh = (unsigned short*)(ws + 140 * MBy);
  unsigned short* Kl = (unsigned short*)(ws + 156 * MBy);
  unsigned short* Vth = (unsigned short*)(ws + 172 * MBy);
  unsigned short* Vtl = (unsigned short*)(ws + 188 * MBy);
  float* scores = (float*)(ws + 0 * MBy);
  unsigned short* Ph = (unsigned short*)(ws + 64 * MBy);
  unsigned short* Pl = (unsigned short*)(ws + 108 * MBy);

  const int n4 = B * S * D / 4;
  split_hl<<<n4 / 256, 256, 0, stream>>>(q, qh, ql, n4);
  split_hl<<<n4 / 256, 256, 0, stream>>>(k, kh, kl, n4);
  split_hl<<<n4 / 256, 256, 0, stream>>>(v, vh, vl, n4);

  wsplit_t<<<dim3(DK / 64, D / 64), 256, 0, stream>>>(Wq, wqth, wqtl, D, DK);
  wsplit_t<<<dim3(DK / 64, D / 64), 256, 0, stream>>>(Wk, wkth, wktl, D, DK);
  wsplit_t<<<dim3(DV / 64, D / 64), 256, 0, stream>>>(Wv, wvth, wvtl, D, DV);

  // projections: one z-batched 8-phase dispatch (z0=Q, z1=K, z2=V^T out)
  {
    GArgs pa{};
    pa.z[0] = {qh, ql, wqth, wqtl, bq, nullptr, Qh, Ql, 1};
    pa.z[1] = {kh, kl, wkth, wktl, bk, nullptr, Kh, Kl, 1};
    pa.z[2] = {vh, vl, wvth, wvtl, bv, nullptr, Vth, Vtl, 2};
    pa.z[3] = pa.z[0];
    pa.N = DK; pa.Kreal = D; pa.nkt = 48; pa.kshift = 4;
    pa.scale = 1.0f; pa.Srows = S;
    gemm8p<<<dim3(DK / 256, (B * S) / 256, 3), 512, 0, stream>>>(pa);
  }

  // scores: per-batch [S,S] = Q @ K^T * (1/32), 8-phase
  {
    GArgs sa{};
    for (int b = 0; b < 4; ++b) {
      sa.z[b] = {Qh + (size_t)b * S * DK, Ql + (size_t)b * S * DK,
                 Kh + (size_t)b * S * DK, Kl + (size_t)b * S * DK,
                 nullptr, scores + (size_t)b * S * S, nullptr, nullptr, 0};
    }
    sa.N = S; sa.Kreal = DK; sa.nkt = 48; sa.kshift = 4;
    sa.scale = 0.03125f; sa.Srows = S;
    gemm8p<<<dim3(S / 256, S / 256, B), 512, 0, stream>>>(sa);
  }

  softmax_rows<<<B * S, 256, 0, stream>>>(scores, Ph, Pl, S);

  // out = P @ V : A = P [S,S], B = V^T [DV,S]  (fused 128^2 kernel)
  gemm_split<0><<<dim3(DV / BN, S / BM, B), 256, 0, stream>>>(
      Ph, Pl, Vth, Vtl, (long)S * S, (long)DV * S, S, DV, S, nullptr, 1.0f,
      (float*)d_out, (long)S * DV, nullptr, nullptr, S);
}

// Round 9
// 842.377 us; speedup vs baseline: 3.7468x; 3.6758x over previous
//
#include <hip/hip_runtime.h>
#include <stdint.h>

// R8: gemm8p de-arrayified. R4/R6 evidence: acc[8][4]+bfr arrays never got
// register-promoted (VGPR=88, 4.9GB scratch writes, MfmaUtil 3.5%) while the
// asm-free gemm_split promotes fine. Fix per rule #20: NAMED scalars for all
// accumulators/fragments (SSA values can't be demoted by asm "memory"
// clobbers). Schedule/swizzle/asm byte-identical to the validated R6 kernel.

typedef __attribute__((ext_vector_type(8))) short short8;
typedef __attribute__((ext_vector_type(4))) float f32x4;
typedef __attribute__((ext_vector_type(4))) unsigned short us4;

#define BM 128
#define BN 128
#define BK 32

static __device__ __forceinline__ unsigned short f2bf(float f) {
  unsigned x = __builtin_bit_cast(unsigned, f);
  x += 0x7fffu + ((x >> 16) & 1u);
  return (unsigned short)(x >> 16);
}
static __device__ __forceinline__ float bf2f(unsigned short u) {
  return __builtin_bit_cast(float, (unsigned)u << 16);
}
static __device__ __forceinline__ void gload_lds16(void* lds, const void* g) {
  __builtin_amdgcn_global_load_lds(
      (const __attribute__((address_space(1))) unsigned int*)g,
      (__attribute__((address_space(3))) unsigned int*)lds, 16, 0, 0);
}

// ---------------- elementwise hi/lo split ----------------
__global__ void __launch_bounds__(256)
split_hl(const float* __restrict__ x, unsigned short* __restrict__ h,
         unsigned short* __restrict__ l, int n4) {
  int i = blockIdx.x * 256 + threadIdx.x;
  if (i >= n4) return;
  float4 v = ((const float4*)x)[i];
  float vv[4] = {v.x, v.y, v.z, v.w};
  us4 hh, ll;
#pragma unroll
  for (int j = 0; j < 4; ++j) {
    unsigned short hi = f2bf(vv[j]);
    hh[j] = hi;
    ll[j] = f2bf(vv[j] - bf2f(hi));
  }
  *(us4*)(h + (size_t)i * 4) = hh;
  *(us4*)(l + (size_t)i * 4) = ll;
}

// ---------------- W: transpose + split ----------------
__global__ void __launch_bounds__(256)
wsplit_t(const float* __restrict__ W, unsigned short* __restrict__ th,
         unsigned short* __restrict__ tl, int K, int N) {
  __shared__ float tile[64][65];
  int k0 = blockIdx.y * 64, n0 = blockIdx.x * 64;
  int t = threadIdx.x;
#pragma unroll
  for (int i = 0; i < 16; ++i) {
    int idx = t + i * 256;
    int r = idx >> 6, c = idx & 63;
    tile[r][c] = W[(size_t)(k0 + r) * N + n0 + c];
  }
  __syncthreads();
#pragma unroll
  for (int i = 0; i < 16; ++i) {
    int idx = t + i * 256;
    int nn = idx >> 6, kk = idx & 63;
    float v = tile[kk][nn];
    unsigned short hi = f2bf(v);
    size_t o = (size_t)(n0 + nn) * K + k0 + kk;
    th[o] = hi;
    tl[o] = f2bf(v - bf2f(hi));
  }
}

// ================= 8-phase 256^2 deep-pipelined GEMM =================
struct ZS {
  const unsigned short *Ah, *Al, *Bh, *Bl;
  const float* bias;
  float* outF;
  unsigned short *outH, *outL;
  int mode;  // 0: fp32 out, 1: split out, 2: transposed split out
};
struct GArgs {
  ZS z[4];
  int N, Kreal, nkt, kshift;
  float scale;
  int Srows;
};

#define STAGE8(MAT, H, KT, BUFI) do {                                          \
    int ktc_ = (KT) < nkt ? (KT) : nkt - 1;                                    \
    int grp_ = ktc_ >> ksh;                                                    \
    const unsigned short* base_ =                                              \
        (MAT) ? ((grp_ == 1) ? Bl_ : Bh_) : ((grp_ == 2) ? Al_ : Ah_);         \
    int rowBase_ = (MAT) ? n0 : m0;                                            \
    int inner_ = (ktc_ & kmask) << 6;                                          \
    _Pragma("unroll")                                                          \
    for (int j_ = 0; j_ < 2; ++j_) {                                           \
      int r_ = j_ * 64 + (tid >> 3);                                           \
      int g_ = (tid & 7) ^ (r_ & 7);                                           \
      gload_lds16(smem + (BUFI) * 65536 + (MAT) * 32768 + (H) * 16384 +        \
                      j_ * 8192 + (tid >> 6) * 1024,                           \
                  base_ + (size_t)(rowBase_ + (H) * 128 + r_) * Kreal +        \
                      inner_ + g_ * 8);                                        \
    }                                                                          \
  } while (0)

#define LDSA8(BUFI, R, ks)                                                     \
  (*(const short8*)(smem + (BUFI) * 65536 + (size_t)(R) * 128 +                \
                    ((((ks) << 2) | lk) ^ ((R) & 7)) * 16))
#define LDSB8(BUFI, R, ks)                                                     \
  (*(const short8*)(smem + (BUFI) * 65536 + 32768 + (size_t)(R) * 128 +        \
                    ((((ks) << 2) | lk) ^ ((R) & 7)) * 16))

// one output row-fragment Mi (named acc), both k-slices
#define MFMA_ROW(Mi, AK0, AK1)                                                 \
  acc_##Mi##_0 = __builtin_amdgcn_mfma_f32_16x16x32_bf16(AK0, bfr_0_0, acc_##Mi##_0, 0, 0, 0); \
  acc_##Mi##_0 = __builtin_amdgcn_mfma_f32_16x16x32_bf16(AK1, bfr_0_1, acc_##Mi##_0, 0, 0, 0); \
  acc_##Mi##_1 = __builtin_amdgcn_mfma_f32_16x16x32_bf16(AK0, bfr_1_0, acc_##Mi##_1, 0, 0, 0); \
  acc_##Mi##_1 = __builtin_amdgcn_mfma_f32_16x16x32_bf16(AK1, bfr_1_1, acc_##Mi##_1, 0, 0, 0); \
  acc_##Mi##_2 = __builtin_amdgcn_mfma_f32_16x16x32_bf16(AK0, bfr_2_0, acc_##Mi##_2, 0, 0, 0); \
  acc_##Mi##_2 = __builtin_amdgcn_mfma_f32_16x16x32_bf16(AK1, bfr_2_1, acc_##Mi##_2, 0, 0, 0); \
  acc_##Mi##_3 = __builtin_amdgcn_mfma_f32_16x16x32_bf16(AK0, bfr_3_0, acc_##Mi##_3, 0, 0, 0); \
  acc_##Mi##_3 = __builtin_amdgcn_mfma_f32_16x16x32_bf16(AK1, bfr_3_1, acc_##Mi##_3, 0, 0, 0);

#define PHASE8(BUFI, M0T, M1T, LOADB, STAGE_STMT, DOVM) do {                   \
    short8 af0k0 = LDSA8(BUFI, wr + (M0T) * 16 + lrow, 0);                     \
    short8 af0k1 = LDSA8(BUFI, wr + (M0T) * 16 + lrow, 1);                     \
    short8 af1k0 = LDSA8(BUFI, wr + (M1T) * 16 + lrow, 0);                     \
    short8 af1k1 = LDSA8(BUFI, wr + (M1T) * 16 + lrow, 1);                     \
    if (LOADB) {                                                               \
      bfr_0_0 = LDSB8(BUFI, wc + 0 * 16 + lrow, 0);                            \
      bfr_0_1 = LDSB8(BUFI, wc + 0 * 16 + lrow, 1);                            \
      bfr_1_0 = LDSB8(BUFI, wc + 1 * 16 + lrow, 0);                            \
      bfr_1_1 = LDSB8(BUFI, wc + 1 * 16 + lrow, 1);                            \
      bfr_2_0 = LDSB8(BUFI, wc + 2 * 16 + lrow, 0);                            \
      bfr_2_1 = LDSB8(BUFI, wc + 2 * 16 + lrow, 1);                            \
      bfr_3_0 = LDSB8(BUFI, wc + 3 * 16 + lrow, 0);                            \
      bfr_3_1 = LDSB8(BUFI, wc + 3 * 16 + lrow, 1);                            \
    }                                                                          \
    STAGE_STMT;                                                                \
    __builtin_amdgcn_sched_barrier(0);                                         \
    if (DOVM) asm volatile("s_waitcnt vmcnt(4)" ::: "memory");                 \
    __builtin_amdgcn_s_barrier();                                              \
    asm volatile("s_waitcnt lgkmcnt(0)" ::: "memory");                         \
    __builtin_amdgcn_sched_barrier(0);                                         \
    __builtin_amdgcn_s_setprio(1);                                             \
    MFMA_ROW(M0T, af0k0, af0k1)                                                \
    MFMA_ROW(M1T, af1k0, af1k1)                                                \
    __builtin_amdgcn_s_setprio(0);                                             \
    __builtin_amdgcn_s_barrier();                                              \
    __builtin_amdgcn_sched_barrier(0);                                         \
  } while (0)

#define EPI(Mi, Ni) do {                                                       \
    int gcol = n0 + wc + (Ni) * 16 + lrow;                                     \
    float bv = bias_ ? bias_[gcol] : 0.0f;                                     \
    _Pragma("unroll")                                                          \
    for (int r = 0; r < 4; ++r) {                                              \
      int grow = m0 + wr + (Mi) * 16 + lk * 4 + r;                             \
      float vv = acc_##Mi##_##Ni[r] * scl + bv;                                \
      if (mode_ == 0) {                                                        \
        outF_[(size_t)grow * N + gcol] = vv;                                   \
      } else if (mode_ == 1) {                                                 \
        unsigned short hi = f2bf(vv);                                          \
        size_t o = (size_t)grow * N + gcol;                                    \
        outH_[o] = hi;                                                         \
        outL_[o] = f2bf(vv - bf2f(hi));                                        \
      } else {                                                                 \
        int bb = grow / Srows_, s = grow - bb * Srows_;                        \
        size_t o = ((size_t)bb * N + gcol) * Srows_ + s;                       \
        unsigned short hi = f2bf(vv);                                          \
        outH_[o] = hi;                                                         \
        outL_[o] = f2bf(vv - bf2f(hi));                                        \
      }                                                                        \
    }                                                                          \
  } while (0)

#define EPI_ROW(Mi) EPI(Mi, 0); EPI(Mi, 1); EPI(Mi, 2); EPI(Mi, 3);

__attribute__((amdgpu_waves_per_eu(1, 2))) __global__ void
__launch_bounds__(512) gemm8p(GArgs ga) {
  __shared__ __align__(16) char smem[131072];
  const int tid = threadIdx.x;
  const int lane = tid & 63;
  const int lrow = lane & 15, lk = lane >> 4;
  const int wid = tid >> 6;
  const int wr = (wid >> 2) * 128;
  const int wc = (wid & 3) * 64;
  const int zb = blockIdx.z;
  // named scalar fields, constant-index kernarg reads (no struct alloca)
  const unsigned short *Ah_, *Al_, *Bh_, *Bl_;
  const float* bias_;
  float* outF_;
  unsigned short *outH_, *outL_;
  int mode_;
  if (zb == 0) {
    Ah_ = ga.z[0].Ah; Al_ = ga.z[0].Al; Bh_ = ga.z[0].Bh; Bl_ = ga.z[0].Bl;
    bias_ = ga.z[0].bias; outF_ = ga.z[0].outF;
    outH_ = ga.z[0].outH; outL_ = ga.z[0].outL; mode_ = ga.z[0].mode;
  } else if (zb == 1) {
    Ah_ = ga.z[1].Ah; Al_ = ga.z[1].Al; Bh_ = ga.z[1].Bh; Bl_ = ga.z[1].Bl;
    bias_ = ga.z[1].bias; outF_ = ga.z[1].outF;
    outH_ = ga.z[1].outH; outL_ = ga.z[1].outL; mode_ = ga.z[1].mode;
  } else if (zb == 2) {
    Ah_ = ga.z[2].Ah; Al_ = ga.z[2].Al; Bh_ = ga.z[2].Bh; Bl_ = ga.z[2].Bl;
    bias_ = ga.z[2].bias; outF_ = ga.z[2].outF;
    outH_ = ga.z[2].outH; outL_ = ga.z[2].outL; mode_ = ga.z[2].mode;
  } else {
    Ah_ = ga.z[3].Ah; Al_ = ga.z[3].Al; Bh_ = ga.z[3].Bh; Bl_ = ga.z[3].Bl;
    bias_ = ga.z[3].bias; outF_ = ga.z[3].outF;
    outH_ = ga.z[3].outH; outL_ = ga.z[3].outL; mode_ = ga.z[3].mode;
  }
  const int m0 = blockIdx.y * 256, n0 = blockIdx.x * 256;
  const int Kreal = ga.Kreal, nkt = ga.nkt, ksh = ga.kshift;
  const int kmask = (1 << ksh) - 1;
  const int N = ga.N;
  const float scl = ga.scale;
  const int Srows_ = ga.Srows;

  // 32 named accumulators + 8 named B-fragments (rule #20: no arrays)
  f32x4 acc_0_0{}, acc_0_1{}, acc_0_2{}, acc_0_3{};
  f32x4 acc_1_0{}, acc_1_1{}, acc_1_2{}, acc_1_3{};
  f32x4 acc_2_0{}, acc_2_1{}, acc_2_2{}, acc_2_3{};
  f32x4 acc_3_0{}, acc_3_1{}, acc_3_2{}, acc_3_3{};
  f32x4 acc_4_0{}, acc_4_1{}, acc_4_2{}, acc_4_3{};
  f32x4 acc_5_0{}, acc_5_1{}, acc_5_2{}, acc_5_3{};
  f32x4 acc_6_0{}, acc_6_1{}, acc_6_2{}, acc_6_3{};
  f32x4 acc_7_0{}, acc_7_1{}, acc_7_2{}, acc_7_3{};
  short8 bfr_0_0, bfr_0_1, bfr_1_0, bfr_1_1;
  short8 bfr_2_0, bfr_2_1, bfr_3_0, bfr_3_1;

  // prologue: A(0),B(0) -> buf0; B(1) -> buf1; wait first 8 of 12 loads.
  STAGE8(0, 0, 0, 0);
  STAGE8(0, 1, 0, 0);
  STAGE8(1, 0, 0, 0);
  STAGE8(1, 1, 0, 0);
  STAGE8(1, 0, 1, 1);
  STAGE8(1, 1, 1, 1);
  __builtin_amdgcn_sched_barrier(0);
  asm volatile("s_waitcnt vmcnt(4)" ::: "memory");
  __builtin_amdgcn_s_barrier();
  __builtin_amdgcn_sched_barrier(0);

  const int niter = nkt >> 1;
  for (int i = 0; i < niter; ++i) {
    int T = 2 * i;
    PHASE8(0, 0, 1, true,  STAGE8(0, 0, T + 1, 1), false);
    PHASE8(0, 2, 3, false, STAGE8(0, 1, T + 1, 1), false);
    PHASE8(0, 4, 5, false, STAGE8(1, 0, T + 2, 0), false);
    PHASE8(0, 6, 7, false, STAGE8(1, 1, T + 2, 0), true);
    PHASE8(1, 0, 1, true,  STAGE8(0, 0, T + 2, 0), false);
    PHASE8(1, 2, 3, false, STAGE8(0, 1, T + 2, 0), false);
    PHASE8(1, 4, 5, false, STAGE8(1, 0, T + 3, 1), false);
    PHASE8(1, 6, 7, false, STAGE8(1, 1, T + 3, 1), true);
  }

  // epilogue: C/D layout col=lane&15, row=(lane>>4)*4+r
  EPI_ROW(0) EPI_ROW(1) EPI_ROW(2) EPI_ROW(3)
  EPI_ROW(4) EPI_ROW(5) EPI_ROW(6) EPI_ROW(7)
}

// ---------------- fused split-bf16 GEMM (128^2, R1-verified) — PV only -------
template <int MODE>
__global__ void __launch_bounds__(256)
gemm_split(const unsigned short* __restrict__ Ah, const unsigned short* __restrict__ Al,
           const unsigned short* __restrict__ Bh, const unsigned short* __restrict__ Bl,
           long sAb, long sBb, int M, int N, int K,
           const float* __restrict__ bias, float scale,
           float* __restrict__ outF, long sOb,
           unsigned short* __restrict__ outH, unsigned short* __restrict__ outL,
           int Srows) {
  __shared__ __align__(16) unsigned short Lds[4 * BM * BK];
  const int t = threadIdx.x;
  const int wave = t >> 6, lane = t & 63;
  const int wr = (wave >> 1) * 64, wc = (wave & 1) * 64;
  const long zb = blockIdx.z;
  const int m0 = blockIdx.y * BM, n0 = blockIdx.x * BN;
  Ah += zb * sAb; Al += zb * sAb;
  Bh += zb * sBb; Bl += zb * sBb;

  f32x4 acc[4][4] = {};
  const int lrow = lane & 15, lk = lane >> 4;
  char* AhT = (char*)Lds;
  char* AlT = AhT + 8192;
  char* BhT = AlT + 8192;
  char* BlT = BhT + 8192;
  const int sw = (lrow >> 1) & 3;
  const int slotB16 = (lk ^ sw) * 16;

  for (int kt = 0; kt < K; kt += BK) {
#pragma unroll
    for (int i = 0; i < 2; ++i) {
      int c = i * 256 + t;
      int row = c >> 2;
      int cs = (c & 3) ^ ((c >> 3) & 3);
      size_t ldsOff = (size_t)(i * 256 + wave * 64) * 16;
      size_t gA = (size_t)(m0 + row) * K + kt + cs * 8;
      size_t gB = (size_t)(n0 + row) * K + kt + cs * 8;
      gload_lds16(AhT + ldsOff, Ah + gA);
      gload_lds16(AlT + ldsOff, Al + gA);
      gload_lds16(BhT + ldsOff, Bh + gB);
      gload_lds16(BlT + ldsOff, Bl + gB);
    }
    __syncthreads();

    const char* Ap[3] = {AhT, AhT, AlT};
    const char* Bp[3] = {BhT, BlT, BhT};
#pragma unroll
    for (int p = 0; p < 3; ++p) {
      short8 af[4], bfv[4];
#pragma unroll
      for (int m = 0; m < 4; ++m)
        af[m] = *(const short8*)(Ap[p] + (size_t)((wr + m * 16 + lrow) * 64) + slotB16);
#pragma unroll
      for (int n = 0; n < 4; ++n)
        bfv[n] = *(const short8*)(Bp[p] + (size_t)((wc + n * 16 + lrow) * 64) + slotB16);
#pragma unroll
      for (int m = 0; m < 4; ++m)
#pragma unroll
        for (int n = 0; n < 4; ++n)
          acc[m][n] = __builtin_amdgcn_mfma_f32_16x16x32_bf16(af[m], bfv[n], acc[m][n], 0, 0, 0);
    }
    __syncthreads();
  }

#pragma unroll
  for (int m = 0; m < 4; ++m) {
#pragma unroll
    for (int n = 0; n < 4; ++n) {
      int gcol = n0 + wc + n * 16 + lrow;
      float bv = bias ? bias[gcol] : 0.0f;
#pragma unroll
      for (int r = 0; r < 4; ++r) {
        int grow = m0 + wr + m * 16 + lk * 4 + r;
        float v = acc[m][n][r] * scale + bv;
        if (MODE == 0) {
          outF[zb * sOb + (size_t)grow * N + gcol] = v;
        } else if (MODE == 1) {
          unsigned short hi = f2bf(v);
          size_t o = (size_t)grow * N + gcol;
          outH[o] = hi;
          outL[o] = f2bf(v - bf2f(hi));
        } else {
          int bb = grow / Srows, s = grow - bb * Srows;
          size_t o = (size_t)bb * N * Srows + (size_t)gcol * Srows + s;
          unsigned short hi = f2bf(v);
          outH[o] = hi;
          outL[o] = f2bf(v - bf2f(hi));
        }
      }
    }
  }
}

// ---------------- row softmax ----------------
__global__ void __launch_bounds__(256)
softmax_rows(const float* __restrict__ sc, unsigned short* __restrict__ ph,
             unsigned short* __restrict__ pl, int S) {
  const size_t row = blockIdx.x;
  const float* sr = sc + row * S;
  int t = threadIdx.x;
  float x[8];
  const float4* s4 = (const float4*)sr;
#pragma unroll
  for (int i = 0; i < 2; ++i) {
    float4 v = s4[t + i * 256];
    x[i * 4 + 0] = v.x; x[i * 4 + 1] = v.y; x[i * 4 + 2] = v.z; x[i * 4 + 3] = v.w;
  }
  float m = x[0];
#pragma unroll
  for (int j = 1; j < 8; ++j) m = fmaxf(m, x[j]);
#pragma unroll
  for (int off = 32; off; off >>= 1) m = fmaxf(m, __shfl_xor(m, off));
  __shared__ float red[4];
  if ((t & 63) == 0) red[t >> 6] = m;
  __syncthreads();
  m = fmaxf(fmaxf(red[0], red[1]), fmaxf(red[2], red[3]));
  float e[8];
  float sum = 0.f;
#pragma unroll
  for (int j = 0; j < 8; ++j) { e[j] = __expf(x[j] - m); sum += e[j]; }
#pragma unroll
  for (int off = 32; off; off >>= 1) sum += __shfl_xor(sum, off);
  __shared__ float red2[4];
  if ((t & 63) == 0) red2[t >> 6] = sum;
  __syncthreads();
  sum = red2[0] + red2[1] + red2[2] + red2[3];
  float rinv = 1.0f / sum;
#pragma unroll
  for (int i = 0; i < 2; ++i) {
    us4 hh, ll;
#pragma unroll
    for (int j = 0; j < 4; ++j) {
      float p = e[i * 4 + j] * rinv;
      unsigned short hi = f2bf(p);
      hh[j] = hi;
      ll[j] = f2bf(p - bf2f(hi));
    }
    size_t o = row * S + (size_t)(t + i * 256) * 4;
    *(us4*)(ph + o) = hh;
    *(us4*)(pl + o) = ll;
  }
}

extern "C" void kernel_launch(void* const* d_in, const int* in_sizes, int n_in,
                              void* d_out, int out_size, void* d_ws, size_t ws_size,
                              hipStream_t stream) {
  const int B = 4, S = 2048, D = 1024, DK = 1024, DV = 1024;
  const float* q = (const float*)d_in[0];
  const float* k = (const float*)d_in[1];
  const float* v = (const float*)d_in[2];
  const float* Wq = (const float*)d_in[3];
  const float* Wk = (const float*)d_in[4];
  const float* Wv = (const float*)d_in[5];
  const float* bq = (const float*)d_in[6];
  const float* bk = (const float*)d_in[7];
  const float* bv = (const float*)d_in[8];

  char* ws = (char*)d_ws;
  const size_t MBy = 1024 * 1024;
  unsigned short* qh = (unsigned short*)(ws + 0 * MBy);
  unsigned short* ql = (unsigned short*)(ws + 16 * MBy);
  unsigned short* kh = (unsigned short*)(ws + 32 * MBy);
  unsigned short* kl = (unsigned short*)(ws + 48 * MBy);
  unsigned short* vh = (unsigned short*)(ws + 64 * MBy);
  unsigned short* vl = (unsigned short*)(ws + 80 * MBy);
  unsigned short* wqth = (unsigned short*)(ws + 96 * MBy);
  unsigned short* wqtl = (unsigned short*)(ws + 98 * MBy);
  unsigned short* wkth = (unsigned short*)(ws + 100 * MBy);
  unsigned short* wktl = (unsigned short*)(ws + 102 * MBy);
  unsigned short* wvth = (unsigned short*)(ws + 104 * MBy);
  unsigned short* wvtl = (unsigned short*)(ws + 106 * MBy);
  unsigned short* Qh = (unsigned short*)(ws + 108 * MBy);
  unsigned short* Ql = (unsigned short*)(ws + 124 * MBy);
  unsigned short* Kh = (unsigned short*)(ws + 140 * MBy);
  unsigned short* Kl = (unsigned short*)(ws + 156 * MBy);
  unsigned short* Vth = (unsigned short*)(ws + 172 * MBy);
  unsigned short* Vtl = (unsigned short*)(ws + 188 * MBy);
  float* scores = (float*)(ws + 0 * MBy);
  unsigned short* Ph = (unsigned short*)(ws + 64 * MBy);
  unsigned short* Pl = (unsigned short*)(ws + 108 * MBy);

  const int n4 = B * S * D / 4;
  split_hl<<<n4 / 256, 256, 0, stream>>>(q, qh, ql, n4);
  split_hl<<<n4 / 256, 256, 0, stream>>>(k, kh, kl, n4);
  split_hl<<<n4 / 256, 256, 0, stream>>>(v, vh, vl, n4);

  wsplit_t<<<dim3(DK / 64, D / 64), 256, 0, stream>>>(Wq, wqth, wqtl, D, DK);
  wsplit_t<<<dim3(DK / 64, D / 64), 256, 0, stream>>>(Wk, wkth, wktl, D, DK);
  wsplit_t<<<dim3(DV / 64, D / 64), 256, 0, stream>>>(Wv, wvth, wvtl, D, DV);

  // projections: one z-batched 8-phase dispatch (z0=Q, z1=K, z2=V^T out)
  {
    GArgs pa{};
    pa.z[0] = {qh, ql, wqth, wqtl, bq, nullptr, Qh, Ql, 1};
    pa.z[1] = {kh, kl, wkth, wktl, bk, nullptr, Kh, Kl, 1};
    pa.z[2] = {vh, vl, wvth, wvtl, bv, nullptr, Vth, Vtl, 2};
    pa.z[3] = pa.z[0];
    pa.N = DK; pa.Kreal = D; pa.nkt = 48; pa.kshift = 4;
    pa.scale = 1.0f; pa.Srows = S;
    gemm8p<<<dim3(DK / 256, (B * S) / 256, 3), 512, 0, stream>>>(pa);
  }

  // scores: per-batch [S,S] = Q @ K^T * (1/32), 8-phase
  {
    GArgs sa{};
    for (int b = 0; b < 4; ++b) {
      sa.z[b] = {Qh + (size_t)b * S * DK, Ql + (size_t)b * S * DK,
                 Kh + (size_t)b * S * DK, Kl + (size_t)b * S * DK,
                 nullptr, scores + (size_t)b * S * S, nullptr, nullptr, 0};
    }
    sa.N = S; sa.Kreal = DK; sa.nkt = 48; sa.kshift = 4;
    sa.scale = 0.03125f; sa.Srows = S;
    gemm8p<<<dim3(S / 256, S / 256, B), 512, 0, stream>>>(sa);
  }

  softmax_rows<<<B * S, 256, 0, stream>>>(scores, Ph, Pl, S);

  // out = P @ V : A = P [S,S], B = V^T [DV,S]  (fused 128^2 kernel)
  gemm_split<0><<<dim3(DV / BN, S / BM, B), 256, 0, stream>>>(
      Ph, Pl, Vth, Vtl, (long)S * S, (long)DV * S, S, DV, S, nullptr, 1.0f,
      (float*)d_out, (long)S * DV, nullptr, nullptr, S);
}